// Round 17
// baseline (232.051 us; speedup 1.0000x reference)
//
#include <hip/hip_runtime.h>
#include <math.h>

// Problem constants (fixed by the reference)
#define BB   2
#define SS   2304
#define DINC 1024
#define DIMC 1024
#define HH   16
#define HD   64

typedef _Float16 half_t;
typedef __attribute__((ext_vector_type(4))) _Float16 half4;   // 2 VGPRs
typedef __attribute__((ext_vector_type(8))) _Float16 half8;   // 4 VGPRs
typedef __attribute__((ext_vector_type(4))) float    f32x4;   // 4 VGPRs

#define LOG2E 1.44269504088896340736f
#define EXP2(x) __builtin_amdgcn_exp2f(x)     // raw v_exp_f32, no libm guard path

// async global->LDS, 16B per lane; LDS dest = wave-uniform base + lane*16
#define GLOAD_LDS16(gp, lp)                                                     \
    __builtin_amdgcn_global_load_lds(                                           \
        (const __attribute__((address_space(1))) void*)(gp),                    \
        (__attribute__((address_space(3))) void*)(lp), 16, 0, 0)

// ---------------------------------------------------------------------------
// Converters, FUSED into one dispatch (r13, kept).
// Body: fp32 row-major [R][K] -> f16 tile-blocked [R/RB][K/32][RB][32].
// ---------------------------------------------------------------------------
template<int RB>
__device__ __forceinline__
void conv_body(const float* __restrict__ src, half_t* __restrict__ dst,
               int K, int mb, int kb, int t)
{
    constexpr int NG = RB * 32 / 1024;       // groups of 1024 elements
    const float* sp0 = src + (size_t)mb * RB * K + kb * 32;
    half_t*      dp0 = dst + ((size_t)mb * (K >> 5) + kb) * (RB * 32);
    #pragma unroll
    for (int g = 0; g < NG; ++g) {
        const int e  = g * 1024 + t * 4;     // flat element in [RB][32] tile
        const int mm = e >> 5, kk = e & 31;
        float4 v = *(const float4*)(sp0 + (size_t)mm * K + kk);
        dp0[e + 0] = (half_t)v.x; dp0[e + 1] = (half_t)v.y;
        dp0[e + 2] = (half_t)v.z; dp0[e + 3] = (half_t)v.w;
    }
}

__global__ __launch_bounds__(256)
void convert_all_f16(const float* __restrict__ input, const float* __restrict__ qkv_w,
                     const float* __restrict__ proj_w, half_t* __restrict__ Ah,
                     half_t* __restrict__ Bh1, half_t* __restrict__ Bh2)
{
    const int bx = blockIdx.x;           // 0..71 : 24 input | 32 qkv_w | 16 proj_w
    const int kb = blockIdx.y;           // 0..31
    const int t  = threadIdx.x;
    if (bx < 24)      conv_body<192>(input, Ah,  DINC, bx,      kb, t);
    else if (bx < 56) conv_body<96>(qkv_w, Bh1, DINC, bx - 24, kb, t);
    else              conv_body<64>(proj_w, Bh2, DIMC, bx - 56, kb, t);
}

// ---------------------------------------------------------------------------
// GEMM1 v2 (r15, PROVEN): 192x96-tile, 768 blocks = 3/CU, 2-phase pipeline,
// LDS-staged vectorized epilogue. Unchanged.
// ---------------------------------------------------------------------------
__global__ __launch_bounds__(256, 3)
void gemm_mfma192(const half_t* __restrict__ Ah, const half_t* __restrict__ Bh,
                  const float* __restrict__ bias, half_t* __restrict__ Cout)
{
    const int t    = threadIdx.x;
    const int w    = t >> 6;
    const int lane = t & 63;
    const int l15  = lane & 15, quad = lane >> 4;
    const int wr   = w >> 1;             // 0,1 : row half (96 rows)
    const int wc   = w & 1;              // 0,1 : col half (48 cols)
    const int mb   = blockIdx.y;         // 0..23
    const int nb   = blockIdx.x;         // 0..31

    // 36 KB: buf u at smem + u*9216 = A(6144) | B(3072). Epilogue reuses all.
    __shared__ __align__(16) half_t smem[18432];

    f32x4 acc[6][3];
    #pragma unroll
    for (int mt = 0; mt < 6; ++mt)
        #pragma unroll
        for (int nt = 0; nt < 3; ++nt) acc[mt][nt] = (f32x4){0.f, 0.f, 0.f, 0.f};

    const half_t* atile = Ah + (size_t)mb * 32 * 6144;
    const half_t* btile = Bh + (size_t)nb * 32 * 3072;

    // stage K-step s into buffer b: 18 chunks (12 A + 6 B) over 4 waves
    #define STAGE192(s, bsel)                                                   \
    {                                                                           \
        const half_t* at = atile + (size_t)(s) * 6144;                          \
        const half_t* bt = btile + (size_t)(s) * 3072;                          \
        half_t* dstA = smem + (bsel) * 9216;                                    \
        half_t* dstB = dstA + 6144;                                             \
        for (int ch = w; ch < 18; ch += 4) {                                    \
            if (ch < 12) GLOAD_LDS16(at + ch * 512 + lane * 8, dstA + ch * 512);\
            else         GLOAD_LDS16(bt + (ch - 12) * 512 + lane * 8,           \
                                     dstB + (ch - 12) * 512);                   \
        }                                                                       \
    }

    STAGE192(0, 0);
    __syncthreads();

    for (int s = 0; s < 32; ++s) {
        const int b = s & 1;
        if (s + 1 < 32) STAGE192(s + 1, b ^ 1);   // issue next BEFORE compute

        const half_t* Au = smem + b * 9216;
        const half_t* Bu = Au + 6144;
        half8 af[6], bf[3];
        #pragma unroll
        for (int mt = 0; mt < 6; ++mt)
            af[mt] = *(const half8*)(Au + (wr * 96 + mt * 16 + l15) * 32 + quad * 8);
        #pragma unroll
        for (int nt = 0; nt < 3; ++nt)
            bf[nt] = *(const half8*)(Bu + (wc * 48 + nt * 16 + l15) * 32 + quad * 8);
        #pragma unroll
        for (int mt = 0; mt < 6; ++mt)
            #pragma unroll
            for (int nt = 0; nt < 3; ++nt)
                acc[mt][nt] = __builtin_amdgcn_mfma_f32_16x16x32_f16(
                    af[mt], bf[nt], acc[mt][nt], 0, 0, 0);

        __syncthreads();   // drains stage(s+1) (issued above, hidden by compute)
    }
    #undef STAGE192

    // ---- epilogue: acc (+bias) -> Cs LDS (f16) -> vectorized stores ----
    const int bm = mb * 192, bn = nb * 96;
    #pragma unroll
    for (int nt = 0; nt < 3; ++nt) {
        const int lc = wc * 48 + nt * 16 + l15;
        const float bv = bias[bn + lc];
        #pragma unroll
        for (int mt = 0; mt < 6; ++mt) {
            const int lr0 = wr * 96 + mt * 16 + quad * 4;
            #pragma unroll
            for (int rg = 0; rg < 4; ++rg)
                smem[(lr0 + rg) * 96 + lc] = (half_t)(acc[mt][nt][rg] + bv);
        }
    }
    __syncthreads();

    #pragma unroll
    for (int i = 0; i < 9; ++i) {
        const int g   = t + 256 * i;         // 0..2303 half8-groups
        const int lr  = g / 12;
        const int lc8 = (g % 12) * 8;
        *(half8*)(Cout + (size_t)(bm + lr) * 3072 + bn + lc8)
            = *(const half8*)(smem + lr * 96 + lc8);
    }
}

// ---------------------------------------------------------------------------
// GEMM2 v3: 48x128-tile f16 MFMA GEMM (NT), M=4608 N=1024 K=1024, fp32 out.
// Old 128x64 grid = 576 blocks = 2.25/CU -> ~25% idle tail (disease fixed in
// r9/r10/r15) + serial stage->barrier->compute. Fix WITHOUT touching attn_h/
// flash: tile 48x128 -> (1024/128)x(4608/48) = 768 blocks = EXACTLY 3/CU.
// A read from existing 128-row-blocked attn_h: 16-row chunks never cross a
// 128-row block boundary (mb*48+16*i = 16-aligned). B = two adjacent 64-row
// Bh2 blocks. 4 waves = 4 col strips (48x32, acc[3][2]); 11 chunks/step
// round-robin; r15-proven 2-phase pipeline. A-chunk addresses computed
// inline (no runtime-indexed pointer array -> no scratch, rule #20).
// fp32 epilogue writes full 64B segments per 16-lane group already.
// ---------------------------------------------------------------------------
__global__ __launch_bounds__(256, 3)
void gemm2_48x128(const half_t* __restrict__ Ah, const half_t* __restrict__ Bh,
                  const float* __restrict__ bias, float* __restrict__ Cout)
{
    const int t    = threadIdx.x;
    const int w    = t >> 6;             // wave = column strip (32 cols)
    const int lane = t & 63;
    const int l15  = lane & 15, quad = lane >> 4;
    const int nb   = blockIdx.x;         // 0..7   (128-col tiles)
    const int mb   = blockIdx.y;         // 0..95  (48-row tiles)

    // buf u at smem + u*5632: A(1536 = 48x32) | B(4096 = 128x32);  22 KB
    __shared__ __align__(16) half_t smem[11264];

    f32x4 acc[3][2];
    #pragma unroll
    for (int mt = 0; mt < 3; ++mt)
        #pragma unroll
        for (int nt = 0; nt < 2; ++nt) acc[mt][nt] = (f32x4){0.f, 0.f, 0.f, 0.f};

    // B: two adjacent 64-row blocks (2nb, 2nb+1) of [blk][kb][64][32]
    const half_t* bsrc0 = Bh + (size_t)(2 * nb + 0) * 32 * 2048;
    const half_t* bsrc1 = Bh + (size_t)(2 * nb + 1) * 32 * 2048;

    // stage K-step s (one kb) into buffer bsel: 3 A chunks + 8 B chunks.
    // A chunk ch (rows mb*48+16*ch .. +15) lives in attn_h [blk][kb][128][32]
    // at blk=(mrow0>>7), row-offset (mrow0&127)*32; inline address calc.
    #define STAGE2(s, bsel)                                                     \
    {                                                                           \
        half_t* dstA = smem + (bsel) * 5632;                                    \
        half_t* dstB = dstA + 1536;                                             \
        for (int ch = w; ch < 11; ch += 4) {                                    \
            if (ch < 3) {                                                       \
                const int mrow0 = mb * 48 + 16 * ch;                            \
                const half_t* ap = Ah + (size_t)(mrow0 >> 7) * 131072           \
                                 + (size_t)(s) * 4096 + (mrow0 & 127) * 32;    \
                GLOAD_LDS16(ap + lane * 8, dstA + ch * 512);                    \
            } else {                                                            \
                const int bc = ch - 3;   /* 0..7: 4 from blk0, 4 from blk1 */   \
                const half_t* bp = (bc < 4 ? bsrc0 : bsrc1)                     \
                                 + (size_t)(s) * 2048 + (bc & 3) * 512;         \
                GLOAD_LDS16(bp + lane * 8, dstB + bc * 512);                    \
            }                                                                   \
        }                                                                       \
    }

    STAGE2(0, 0);
    __syncthreads();

    for (int s = 0; s < 32; ++s) {
        const int b = s & 1;
        if (s + 1 < 32) STAGE2(s + 1, b ^ 1);   // issue next BEFORE compute

        const half_t* Au = smem + b * 5632;
        const half_t* Bu = Au + 1536;
        half8 af[3], bf[2];
        #pragma unroll
        for (int mt = 0; mt < 3; ++mt)
            af[mt] = *(const half8*)(Au + (mt * 16 + l15) * 32 + quad * 8);
        #pragma unroll
        for (int nt = 0; nt < 2; ++nt)
            bf[nt] = *(const half8*)(Bu + (w * 32 + nt * 16 + l15) * 32 + quad * 8);
        #pragma unroll
        for (int mt = 0; mt < 3; ++mt)
            #pragma unroll
            for (int nt = 0; nt < 2; ++nt)
                acc[mt][nt] = __builtin_amdgcn_mfma_f32_16x16x32_f16(
                    af[mt], bf[nt], acc[mt][nt], 0, 0, 0);

        __syncthreads();   // drains stage(s+1), hidden by compute
    }
    #undef STAGE2

    const int bm = mb * 48, bn = nb * 128;
    #pragma unroll
    for (int nt = 0; nt < 2; ++nt) {
        const int n  = bn + w * 32 + nt * 16 + l15;
        const float bv = bias[n];
        #pragma unroll
        for (int mt = 0; mt < 3; ++mt) {
            const int m0 = bm + mt * 16 + quad * 4;
            #pragma unroll
            for (int rg = 0; rg < 4; ++rg)
                Cout[(size_t)(m0 + rg) * 1024 + n] = acc[mt][nt][rg] + bv;
        }
    }
}

// ---------------------------------------------------------------------------
// normrope_v8 (r14, kept): RMSNorm + axial 2D RoPE, LDS-staged vectorized
// Q/K stores (16B half8); V scatter unchanged (irreducible per-token).
// ---------------------------------------------------------------------------
__global__ __launch_bounds__(256)
void normrope_v8(half_t* __restrict__ qkvh, const float* __restrict__ q_scale,
                 const float* __restrict__ k_scale, const int* __restrict__ wptr,
                 half_t* __restrict__ Kf, half_t* __restrict__ Vf)
{
    const int token = blockIdx.x;        // b*SS + s
    const int s     = token % SS;
    const int b     = token / SS;
    const int w     = *wptr;
    const int t     = threadIdx.x;
    const float rowp = (float)(s / w);
    const float colp = (float)(s % w);

    half_t* base = qkvh + (size_t)token * 3072;

    const int c    = s >> 5;             // 32-token chunk
    const int slot = s & 31;
    const int ktile = (slot >> 2) & 1;
    const int krow  = ((slot >> 3) << 2) + (slot & 3);

    // ---- V -> Vf (16x16x32 A-operand tiles, k = slot; scatter) ----
    {
        half4 v4 = *(const half4*)(base + 2048 + 4 * t);
        const int dabs0 = 4 * t;
        const int h  = dabs0 >> 6;
        const int sl3 = slot >> 3, sl7 = slot & 7;
        half_t* vdst = Vf + ((size_t)(b * HH + h) * 72 + c) * 2048;
        #pragma unroll
        for (int ii = 0; ii < 4; ++ii) {
            const int d = (dabs0 + ii) & 63;
            vdst[(d >> 4) * 512 + (sl3 * 16 + (d & 15)) * 8 + sl7] = v4[ii];
        }
    }

    __shared__ float buf[DIMC];
    __shared__ float red[4];
    __shared__ __align__(16) half_t obuf[DIMC];   // staged roped outputs (f16)

    #pragma unroll
    for (int sel = 0; sel < 2; ++sel) {
        half_t* row = base + sel * DIMC;
        const float* scp = sel ? k_scale : q_scale;

        half4 xh = *(const half4*)(row + 4 * t);
        float x0 = (float)xh[0], x1 = (float)xh[1], x2 = (float)xh[2], x3 = (float)xh[3];
        float ss = x0 * x0 + x1 * x1 + x2 * x2 + x3 * x3;
        #pragma unroll
        for (int o = 32; o >= 1; o >>= 1) ss += __shfl_xor(ss, o);
        if ((t & 63) == 0) red[t >> 6] = ss;
        __syncthreads();

        const float rinv = rsqrtf((red[0] + red[1] + red[2] + red[3]) * (1.0f / DIMC) + 1e-6f);
        float4 g = *(const float4*)(scp + 4 * t);
        buf[4 * t + 0] = x0 * rinv * g.x;
        buf[4 * t + 1] = x1 * rinv * g.y;
        buf[4 * t + 2] = x2 * rinv * g.z;
        buf[4 * t + 3] = x3 * rinv * g.w;
        __syncthreads();

        const float qsc = sel ? 1.0f : (0.125f * LOG2E);  // log2-domain scores

        #pragma unroll
        for (int pp = 0; pp < 2; ++pp) {
            const int p = t + pp * 256;
            const int h = p >> 5;
            const int r = p & 31;
            const int j = r & 15;
            const float pos = (r < 16) ? rowp : colp;
            const int d1 = (r < 16) ? j : (32 + j);   // within-head dim
            const int d2 = d1 + 16;
            const float freq = exp2f((float)j * -0.83048202372f);
            const float ang  = pos * freq;
            float sn, cs;
            __sincosf(ang, &sn, &cs);
            const float a1 = buf[h * HD + d1], a2 = buf[h * HD + d2];
            obuf[h * HD + d1] = (half_t)((a1 * cs - a2 * sn) * qsc);
            obuf[h * HD + d2] = (half_t)((a2 * cs + a1 * sn) * qsc);
        }
        __syncthreads();

        // ---- vectorized store: 128 threads x one half8 (16B) each ----
        if (t < 128) {
            if (sel == 0) {
                *(half8*)(row + t * 8) = *(const half8*)(obuf + t * 8);
            } else {
                const int h = t >> 3, grp = t & 7;
                half_t* kdst = Kf + ((size_t)(b * HH + h) * 72 + c) * 2048;
                const int off = (((ktile << 1) + (grp >> 2)) << 9)
                              + ((((grp & 3) << 4) + krow) << 3);
                *(half8*)(kdst + off) = *(const half8*)(obuf + h * HD + grp * 8);
            }
        }
        __syncthreads();   // buf/red/obuf reused by next sel
    }
}

// ---------------------------------------------------------------------------
// Flash attention v17 (r11, PROVEN ~46-48us): 96-row q-tile, 768 blocks =
// exactly 3/CU, no-max softmax, K=32 PV, dist-1 dead-reg prefetch, l via
// ones-row MFMA, O-store to 128-row-blocked attn_h. Unchanged.
// ---------------------------------------------------------------------------
__global__ __launch_bounds__(256, 3)
void flash_attn_mfma17(const half_t* __restrict__ qkvh, const half_t* __restrict__ Kf,
                       const half_t* __restrict__ Vf, half_t* __restrict__ attn_h)
{
    const int flat = blockIdx.x;         // 0..767, XCD-swizzled
    const int xcd  = flat & 7;
    const int idx  = flat >> 3;          // 0..95  (96 per XCD = exactly 4 bh)
    const int bh   = xcd * 4 + idx / 24;
    const int qtb  = idx % 24;
    const int b    = bh >> 4, h = bh & 15;
    const int t    = threadIdx.x;
    const int w    = t >> 6;
    const int qh   = w >> 1;             // wave's q-half (48 rows)
    const int jt   = w & 1;              // wave's chunk parity
    const int lane = t & 63;
    const int l15  = lane & 15, quad = lane >> 4;

    const size_t tb = (size_t)b * SS;
    const int q0 = qtb * 96;

    __shared__ float mlb[4][48];         // per-wave l for its 48 q's
    __shared__ float Ob[2][64][49];      // [qh][d][q(48)], padded stride 49

    // Q B-frags (loop invariant): B[k=quad*8+i][n=l15], 3 q-tiles x 2 d-groups
    half8 qf[3][2];
    #pragma unroll
    for (int qt = 0; qt < 3; ++qt)
        #pragma unroll
        for (int dg = 0; dg < 2; ++dg)
            qf[qt][dg] = *(const half8*)(qkvh + (tb + q0 + qh * 48 + qt * 16 + l15) * 3072
                                          + h * HD + dg * 32 + quad * 8);

    // ones A-frag: A[m][k] = (m==0). Lane (l15,quad) holds A[l15][quad*8+i].
    const half8 onesA = (l15 == 0)
        ? (half8){(half_t)1, (half_t)1, (half_t)1, (half_t)1,
                  (half_t)1, (half_t)1, (half_t)1, (half_t)1}
        : (half8){(half_t)0, (half_t)0, (half_t)0, (half_t)0,
                  (half_t)0, (half_t)0, (half_t)0, (half_t)0};

    f32x4 acc[4][3];                     // [dt][qt] : O^T[dt*16+quad*4+reg][q]
    f32x4 acc5[3];                       // l-row: acc5[qt][0]@quad0 = l(q=l15)
    #pragma unroll
    for (int qt = 0; qt < 3; ++qt) {
        acc5[qt] = (f32x4){0.f, 0.f, 0.f, 0.f};
        #pragma unroll
        for (int dt = 0; dt < 4; ++dt) acc[dt][qt] = (f32x4){0.f, 0.f, 0.f, 0.f};
    }

    // wave's chunk pointers: wave-chunk p -> global chunk (2p + jt)
    const half_t* kpl = Kf + (size_t)bh * 147456 + jt * 2048 + lane * 8;
    const half_t* vpl = Vf + (size_t)bh * 147456 + jt * 2048 + lane * 8;

    // initial chunk (separate K and V buffers)
    half8 k00 = *(const half8*)(kpl);            // tile0, d 0..31
    half8 k01 = *(const half8*)(kpl + 512);      // tile0, d 32..63
    half8 k10 = *(const half8*)(kpl + 1024);     // tile1, d 0..31
    half8 k11 = *(const half8*)(kpl + 1536);     // tile1, d 32..63
    half8 v0  = *(const half8*)(vpl);            // dt A-frags (k=slot)
    half8 v1  = *(const half8*)(vpl + 512);
    half8 v2  = *(const half8*)(vpl + 1024);
    half8 v3  = *(const half8*)(vpl + 1536);

    const f32x4 initC = (f32x4){-4.f, -4.f, -4.f, -4.f};   // P = exp2(s - 4)

    for (int p = 0; p < 36; ++p) {
        // ---- S^T both 16-row tiles x 3 q-tiles (k regs dead afterwards) ----
        f32x4 scA[3], scB[3];
        __builtin_amdgcn_s_setprio(1);
        #pragma unroll
        for (int qt = 0; qt < 3; ++qt) {
            scA[qt] = initC;
            scA[qt] = __builtin_amdgcn_mfma_f32_16x16x32_f16(k00, qf[qt][0], scA[qt], 0, 0, 0);
            scA[qt] = __builtin_amdgcn_mfma_f32_16x16x32_f16(k01, qf[qt][1], scA[qt], 0, 0, 0);
            scB[qt] = initC;
            scB[qt] = __builtin_amdgcn_mfma_f32_16x16x32_f16(k10, qf[qt][0], scB[qt], 0, 0, 0);
            scB[qt] = __builtin_amdgcn_mfma_f32_16x16x32_f16(k11, qf[qt][1], scB[qt], 0, 0, 0);
        }
        __builtin_amdgcn_s_setprio(0);

        // ---- prefetch next chunk's K into the now-dead k regs ----
        if (p + 1 < 36) {
            const half_t* kN = kpl + (size_t)(p + 1) * 4096;
            k00 = *(const half8*)(kN);
            k01 = *(const half8*)(kN + 512);
            k10 = *(const half8*)(kN + 1024);
            k11 = *(const half8*)(kN + 1536);
        }

        // ---- no-max softmax: P = exp2(s-4) directly (l done by MFMA) ----
        half8 pf[3];
        #pragma unroll
        for (int qt = 0; qt < 3; ++qt) {
            const float a0 = EXP2(scA[qt][0]);
            const float a1 = EXP2(scA[qt][1]);
            const float a2 = EXP2(scA[qt][2]);
            const float a3 = EXP2(scA[qt][3]);
            const float b0 = EXP2(scB[qt][0]);
            const float b1 = EXP2(scB[qt][1]);
            const float b2 = EXP2(scB[qt][2]);
            const float b3 = EXP2(scB[qt][3]);
            // lane quad q' holds P for slots 8q'..8q'+7 -> contiguous B-frag
            pf[qt] = (half8){(half_t)a0, (half_t)a1, (half_t)a2, (half_t)a3,
                             (half_t)b0, (half_t)b1, (half_t)b2, (half_t)b3};
        }

        // ---- O^T += V^T.P^T ; l-row += 1.P^T (v regs dead afterwards) ----
        __builtin_amdgcn_s_setprio(1);
        #pragma unroll
        for (int dt = 0; dt < 4; ++dt) {
            const half8 vf = (dt == 0) ? v0 : (dt == 1) ? v1 : (dt == 2) ? v2 : v3;
            #pragma unroll
            for (int qt = 0; qt < 3; ++qt)
                acc[dt][qt] = __builtin_amdgcn_mfma_f32_16x16x32_f16(
                    vf, pf[qt], acc[dt][qt], 0, 0, 0);
        }
        #pragma unroll
        for (int qt = 0; qt < 3; ++qt)
            acc5[qt] = __builtin_amdgcn_mfma_f32_16x16x32_f16(
                onesA, pf[qt], acc5[qt], 0, 0, 0);
        __builtin_amdgcn_s_setprio(0);

        // ---- prefetch next chunk's V into the now-dead v regs ----
        if (p + 1 < 36) {
            const half_t* vN = vpl + (size_t)(p + 1) * 4096;
            v0 = *(const half8*)(vN);
            v1 = *(const half8*)(vN + 512);
            v2 = *(const half8*)(vN + 1024);
            v3 = *(const half8*)(vN + 1536);
        }
    }

    // ---- 2-way merge across jt waves, per q-half (l from acc5 row 0) ----
    #pragma unroll
    for (int qt = 0; qt < 3; ++qt)
        if (quad == 0) mlb[w][qt * 16 + l15] = acc5[qt][0];
    __syncthreads();

    float fac[3];
    #pragma unroll
    for (int qt = 0; qt < 3; ++qt) {
        const int q = qt * 16 + l15;
        fac[qt] = 1.0f / (mlb[qh * 2 + 0][q] + mlb[qh * 2 + 1][q]);
    }

    #pragma unroll
    for (int ph = 0; ph < 2; ++ph) {
        if (jt == ph) {
            #pragma unroll
            for (int dt = 0; dt < 4; ++dt)
                #pragma unroll
                for (int qt = 0; qt < 3; ++qt)
                    #pragma unroll
                    for (int rg = 0; rg < 4; ++rg) {
                        const int d = dt * 16 + quad * 4 + rg;
                        const int q = qt * 16 + l15;
                        const float v = acc[dt][qt][rg] * fac[qt];
                        if (ph == 0) Ob[qh][d][q] = v;
                        else         Ob[qh][d][q] += v;
                    }
        }
        __syncthreads();
    }

    // ---- store O as f16, tile-blocked [mb][kb][128][32] for the proj GEMM ----
    // 96 rows x 64 d = 6144 halfs; 3 groups of 32 rows, 8 threads/row x 8 d.
    #pragma unroll
    for (int g2 = 0; g2 < 3; ++g2) {
        const int q  = g2 * 32 + (t >> 3);   // 0..95
        const int ds = (t & 7) * 8;          // 0..56, 8-aligned
        const int qh2 = (q >= 48) ? 1 : 0;
        const int qq  = q - 48 * qh2;
        const size_t mrow = tb + q0 + q;
        const int mb2 = (int)(mrow >> 7);
        const int mm  = (int)(mrow & 127);
        const int kb2 = (h * HD + ds) >> 5;
        const int kk  = ds & 31;
        half8 o;
        #pragma unroll
        for (int ii = 0; ii < 8; ++ii) o[ii] = (half_t)Ob[qh2][ds + ii][qq];
        *(half8*)(attn_h + ((size_t)mb2 * 32 + kb2) * 4096 + mm * 32 + kk) = o;
    }
}

// ---------------------------------------------------------------------------
// Launch
// ---------------------------------------------------------------------------
extern "C" void kernel_launch(void* const* d_in, const int* in_sizes, int n_in,
                              void* d_out, int out_size, void* d_ws, size_t ws_size,
                              hipStream_t stream)
{
    const float* input   = (const float*)d_in[0];
    const float* qkv_w   = (const float*)d_in[1];
    const float* qkv_b   = (const float*)d_in[2];
    const float* q_scale = (const float*)d_in[3];
    const float* k_scale = (const float*)d_in[4];
    const float* proj_w  = (const float*)d_in[5];
    const float* proj_b  = (const float*)d_in[6];
    const int*   width   = (const int*)d_in[8];
    float* out = (float*)d_out;

    // ws layout (all f16): qkv_h 28.3MB | attn_h 9.4 | Vf 9.4 | Ah 9.4 (reused
    // as Kf after GEMM1) | Bh1 6.3 | Bh2 2.1  => 65.0 MB total
    half_t* qkvh   = (half_t*)d_ws;
    half_t* attn_h = qkvh   + (size_t)4608 * 3072;
    half_t* Vf     = attn_h + (size_t)4608 * 1024;
    half_t* Ah     = Vf     + (size_t)32 * 72 * 2048;
    half_t* Bh1    = Ah     + (size_t)4608 * 1024;
    half_t* Bh2    = Bh1    + (size_t)3072 * 1024;
    half_t* Kf     = Ah;    // Ah is dead after GEMM1; Kf is written by normrope

    const int M = BB * SS;   // 4608

    // 0) fp32 -> f16 tile-blocked converters, FUSED into one dispatch
    convert_all_f16<<<dim3(72, 32), 256, 0, stream>>>(input, qkv_w, proj_w,
                                                      Ah, Bh1, Bh2);

    // 1) qkv_h = f16( input @ qkv_w^T + qkv_b )  -- 192x96 tiles, 768 blocks
    gemm_mfma192<<<dim3(3 * DIMC / 96, M / 192), 256, 0, stream>>>(
        Ah, Bh1, qkv_b, qkvh);

    // 2) RMSNorm + RoPE: Q in place (log2-scaled), K -> Kf, V -> Vf
    normrope_v8<<<M, 256, 0, stream>>>(qkvh, q_scale, k_scale, width, Kf, Vf);

    // 3) MFMA flash attention -> attn_h (f16, 128-row-blocked), XCD-swizzled
    flash_attn_mfma17<<<dim3(768), 256, 0, stream>>>(qkvh, Kf, Vf, attn_h);

    // 4) out = attn @ proj_w^T + proj_b  -- 48x128 tiles, 768 blocks = 3/CU
    gemm2_48x128<<<dim3(DINC / 128, M / 48), 256, 0, stream>>>(
        attn_h, Bh2, proj_b, out);
}

// Round 18
// 224.389 us; speedup vs baseline: 1.0341x; 1.0341x over previous
//
#include <hip/hip_runtime.h>
#include <math.h>

// Problem constants (fixed by the reference)
#define BB   2
#define SS   2304
#define DINC 1024
#define DIMC 1024
#define HH   16
#define HD   64

typedef _Float16 half_t;
typedef __attribute__((ext_vector_type(4))) _Float16 half4;   // 2 VGPRs
typedef __attribute__((ext_vector_type(8))) _Float16 half8;   // 4 VGPRs
typedef __attribute__((ext_vector_type(4))) float    f32x4;   // 4 VGPRs

#define LOG2E 1.44269504088896340736f
#define EXP2(x) __builtin_amdgcn_exp2f(x)     // raw v_exp_f32, no libm guard path

// async global->LDS, 16B per lane; LDS dest = wave-uniform base + lane*16
#define GLOAD_LDS16(gp, lp)                                                     \
    __builtin_amdgcn_global_load_lds(                                           \
        (const __attribute__((address_space(1))) void*)(gp),                    \
        (__attribute__((address_space(3))) void*)(lp), 16, 0, 0)

// ---------------------------------------------------------------------------
// Converters, FUSED into one dispatch (r13, kept).
// Body: fp32 row-major [R][K] -> f16 tile-blocked [R/RB][K/32][RB][32].
// ---------------------------------------------------------------------------
template<int RB>
__device__ __forceinline__
void conv_body(const float* __restrict__ src, half_t* __restrict__ dst,
               int K, int mb, int kb, int t)
{
    constexpr int NG = RB * 32 / 1024;       // groups of 1024 elements
    const float* sp0 = src + (size_t)mb * RB * K + kb * 32;
    half_t*      dp0 = dst + ((size_t)mb * (K >> 5) + kb) * (RB * 32);
    #pragma unroll
    for (int g = 0; g < NG; ++g) {
        const int e  = g * 1024 + t * 4;     // flat element in [RB][32] tile
        const int mm = e >> 5, kk = e & 31;
        float4 v = *(const float4*)(sp0 + (size_t)mm * K + kk);
        dp0[e + 0] = (half_t)v.x; dp0[e + 1] = (half_t)v.y;
        dp0[e + 2] = (half_t)v.z; dp0[e + 3] = (half_t)v.w;
    }
}

__global__ __launch_bounds__(256)
void convert_all_f16(const float* __restrict__ input, const float* __restrict__ qkv_w,
                     const float* __restrict__ proj_w, half_t* __restrict__ Ah,
                     half_t* __restrict__ Bh1, half_t* __restrict__ Bh2)
{
    const int bx = blockIdx.x;           // 0..71 : 24 input | 32 qkv_w | 16 proj_w
    const int kb = blockIdx.y;           // 0..31
    const int t  = threadIdx.x;
    if (bx < 24)      conv_body<192>(input, Ah,  DINC, bx,      kb, t);
    else if (bx < 56) conv_body<96>(qkv_w, Bh1, DINC, bx - 24, kb, t);
    else              conv_body<64>(proj_w, Bh2, DIMC, bx - 56, kb, t);
}

// ---------------------------------------------------------------------------
// GEMM1 v2 (r15, PROVEN): 192x96-tile, 768 blocks = 3/CU, 2-phase pipeline,
// LDS-staged vectorized epilogue. Unchanged.
// ---------------------------------------------------------------------------
__global__ __launch_bounds__(256, 3)
void gemm_mfma192(const half_t* __restrict__ Ah, const half_t* __restrict__ Bh,
                  const float* __restrict__ bias, half_t* __restrict__ Cout)
{
    const int t    = threadIdx.x;
    const int w    = t >> 6;
    const int lane = t & 63;
    const int l15  = lane & 15, quad = lane >> 4;
    const int wr   = w >> 1;             // 0,1 : row half (96 rows)
    const int wc   = w & 1;              // 0,1 : col half (48 cols)
    const int mb   = blockIdx.y;         // 0..23
    const int nb   = blockIdx.x;         // 0..31

    // 36 KB: buf u at smem + u*9216 = A(6144) | B(3072). Epilogue reuses all.
    __shared__ __align__(16) half_t smem[18432];

    f32x4 acc[6][3];
    #pragma unroll
    for (int mt = 0; mt < 6; ++mt)
        #pragma unroll
        for (int nt = 0; nt < 3; ++nt) acc[mt][nt] = (f32x4){0.f, 0.f, 0.f, 0.f};

    const half_t* atile = Ah + (size_t)mb * 32 * 6144;
    const half_t* btile = Bh + (size_t)nb * 32 * 3072;

    // stage K-step s into buffer b: 18 chunks (12 A + 6 B) over 4 waves
    #define STAGE192(s, bsel)                                                   \
    {                                                                           \
        const half_t* at = atile + (size_t)(s) * 6144;                          \
        const half_t* bt = btile + (size_t)(s) * 3072;                          \
        half_t* dstA = smem + (bsel) * 9216;                                    \
        half_t* dstB = dstA + 6144;                                             \
        for (int ch = w; ch < 18; ch += 4) {                                    \
            if (ch < 12) GLOAD_LDS16(at + ch * 512 + lane * 8, dstA + ch * 512);\
            else         GLOAD_LDS16(bt + (ch - 12) * 512 + lane * 8,           \
                                     dstB + (ch - 12) * 512);                   \
        }                                                                       \
    }

    STAGE192(0, 0);
    __syncthreads();

    for (int s = 0; s < 32; ++s) {
        const int b = s & 1;
        if (s + 1 < 32) STAGE192(s + 1, b ^ 1);   // issue next BEFORE compute

        const half_t* Au = smem + b * 9216;
        const half_t* Bu = Au + 6144;
        half8 af[6], bf[3];
        #pragma unroll
        for (int mt = 0; mt < 6; ++mt)
            af[mt] = *(const half8*)(Au + (wr * 96 + mt * 16 + l15) * 32 + quad * 8);
        #pragma unroll
        for (int nt = 0; nt < 3; ++nt)
            bf[nt] = *(const half8*)(Bu + (wc * 48 + nt * 16 + l15) * 32 + quad * 8);
        #pragma unroll
        for (int mt = 0; mt < 6; ++mt)
            #pragma unroll
            for (int nt = 0; nt < 3; ++nt)
                acc[mt][nt] = __builtin_amdgcn_mfma_f32_16x16x32_f16(
                    af[mt], bf[nt], acc[mt][nt], 0, 0, 0);

        __syncthreads();   // drains stage(s+1) (issued above, hidden by compute)
    }
    #undef STAGE192

    // ---- epilogue: acc (+bias) -> Cs LDS (f16) -> vectorized stores ----
    const int bm = mb * 192, bn = nb * 96;
    #pragma unroll
    for (int nt = 0; nt < 3; ++nt) {
        const int lc = wc * 48 + nt * 16 + l15;
        const float bv = bias[bn + lc];
        #pragma unroll
        for (int mt = 0; mt < 6; ++mt) {
            const int lr0 = wr * 96 + mt * 16 + quad * 4;
            #pragma unroll
            for (int rg = 0; rg < 4; ++rg)
                smem[(lr0 + rg) * 96 + lc] = (half_t)(acc[mt][nt][rg] + bv);
        }
    }
    __syncthreads();

    #pragma unroll
    for (int i = 0; i < 9; ++i) {
        const int g   = t + 256 * i;         // 0..2303 half8-groups
        const int lr  = g / 12;
        const int lc8 = (g % 12) * 8;
        *(half8*)(Cout + (size_t)(bm + lr) * 3072 + bn + lc8)
            = *(const half8*)(smem + lr * 96 + lc8);
    }
}

// ---------------------------------------------------------------------------
// GEMM2 v4: 128x64-tile f16 MFMA GEMM (NT), M=4608 N=1024 K=1024, fp32 out.
// r17 lesson: the 48x128 exact-divisor re-tile TRIPLED B re-reads (M-tile
// 128->48 cuts B reuse) and regressed +7us -- grid-quantization fixes must
// preserve operand reuse. Revert to the proven 128x64 tile (576 blocks) and
// apply ONLY the r15-proven 2-phase pipeline to its main loop: old structure
// staged a kb-pair then barrier'd with zero compute in flight; now STAGE(s+1)
// issues BEFORE compute(s), one barrier per step (drains the stage under the
// 16 MFMAs and protects the buffer swap). Tile/layout/epilogue unchanged
// (fp32 epilogue already writes full 64B segments per 16-lane quad).
// ---------------------------------------------------------------------------
__global__ __launch_bounds__(256)
void gemm2_128x64(const half_t* __restrict__ Ah, const half_t* __restrict__ Bh,
                  const float* __restrict__ bias, float* __restrict__ Cout)
{
    const int t    = threadIdx.x;
    const int w    = t >> 6;             // wave = row quarter (32 rows)
    const int lane = t & 63;
    const int l15  = lane & 15, quad = lane >> 4;
    const int nb   = blockIdx.x;         // 0..15 (64-col tiles)
    const int mb   = blockIdx.y;         // 0..35 (128-row tiles)

    // buf u at smem + u*6144: A(4096 = 128x32) | B(2048 = 64x32);  24 KB
    __shared__ __align__(16) half_t smem[12288];

    f32x4 acc[2][4];                     // [mt][nt]: rows w*32+mt*16, cols nt*16
    #pragma unroll
    for (int mt = 0; mt < 2; ++mt)
        #pragma unroll
        for (int nt = 0; nt < 4; ++nt) acc[mt][nt] = (f32x4){0.f, 0.f, 0.f, 0.f};

    const half_t* atile = Ah + (size_t)mb * 32 * 4096;
    const half_t* btile = Bh + (size_t)nb * 32 * 2048;

    // stage K-step s into buffer bsel: 8 A chunks (2/wave) + 4 B chunks (1/wave)
    #define STAGE2(s, bsel)                                                     \
    {                                                                           \
        const half_t* at = atile + (size_t)(s) * 4096;                          \
        const half_t* bt = btile + (size_t)(s) * 2048;                          \
        half_t* dstA = smem + (bsel) * 6144;                                    \
        half_t* dstB = dstA + 4096;                                             \
        GLOAD_LDS16(at + (w * 2 + 0) * 512 + lane * 8, dstA + (w * 2 + 0) * 512);\
        GLOAD_LDS16(at + (w * 2 + 1) * 512 + lane * 8, dstA + (w * 2 + 1) * 512);\
        GLOAD_LDS16(bt + w * 512 + lane * 8, dstB + w * 512);                   \
    }

    STAGE2(0, 0);
    __syncthreads();

    for (int s = 0; s < 32; ++s) {
        const int b = s & 1;
        if (s + 1 < 32) STAGE2(s + 1, b ^ 1);   // issue next BEFORE compute

        const half_t* Au = smem + b * 6144;
        const half_t* Bu = Au + 4096;
        half8 af[2], bf[4];
        #pragma unroll
        for (int mt = 0; mt < 2; ++mt)
            af[mt] = *(const half8*)(Au + (w * 32 + mt * 16 + l15) * 32 + quad * 8);
        #pragma unroll
        for (int nt = 0; nt < 4; ++nt)
            bf[nt] = *(const half8*)(Bu + (nt * 16 + l15) * 32 + quad * 8);
        #pragma unroll
        for (int mt = 0; mt < 2; ++mt)
            #pragma unroll
            for (int nt = 0; nt < 4; ++nt)
                acc[mt][nt] = __builtin_amdgcn_mfma_f32_16x16x32_f16(
                    af[mt], bf[nt], acc[mt][nt], 0, 0, 0);

        __syncthreads();   // drains stage(s+1), hidden by compute
    }
    #undef STAGE2

    const int bm = mb * 128, bn = nb * 64;
    #pragma unroll
    for (int nt = 0; nt < 4; ++nt) {
        const int n  = bn + nt * 16 + l15;
        const float bv = bias[n];
        #pragma unroll
        for (int mt = 0; mt < 2; ++mt) {
            const int m0 = bm + w * 32 + mt * 16 + quad * 4;
            #pragma unroll
            for (int rg = 0; rg < 4; ++rg)
                Cout[(size_t)(m0 + rg) * 1024 + n] = acc[mt][nt][rg] + bv;
        }
    }
}

// ---------------------------------------------------------------------------
// normrope_v8 (r14, kept): RMSNorm + axial 2D RoPE, LDS-staged vectorized
// Q/K stores (16B half8); V scatter unchanged (irreducible per-token).
// ---------------------------------------------------------------------------
__global__ __launch_bounds__(256)
void normrope_v8(half_t* __restrict__ qkvh, const float* __restrict__ q_scale,
                 const float* __restrict__ k_scale, const int* __restrict__ wptr,
                 half_t* __restrict__ Kf, half_t* __restrict__ Vf)
{
    const int token = blockIdx.x;        // b*SS + s
    const int s     = token % SS;
    const int b     = token / SS;
    const int w     = *wptr;
    const int t     = threadIdx.x;
    const float rowp = (float)(s / w);
    const float colp = (float)(s % w);

    half_t* base = qkvh + (size_t)token * 3072;

    const int c    = s >> 5;             // 32-token chunk
    const int slot = s & 31;
    const int ktile = (slot >> 2) & 1;
    const int krow  = ((slot >> 3) << 2) + (slot & 3);

    // ---- V -> Vf (16x16x32 A-operand tiles, k = slot; scatter) ----
    {
        half4 v4 = *(const half4*)(base + 2048 + 4 * t);
        const int dabs0 = 4 * t;
        const int h  = dabs0 >> 6;
        const int sl3 = slot >> 3, sl7 = slot & 7;
        half_t* vdst = Vf + ((size_t)(b * HH + h) * 72 + c) * 2048;
        #pragma unroll
        for (int ii = 0; ii < 4; ++ii) {
            const int d = (dabs0 + ii) & 63;
            vdst[(d >> 4) * 512 + (sl3 * 16 + (d & 15)) * 8 + sl7] = v4[ii];
        }
    }

    __shared__ float buf[DIMC];
    __shared__ float red[4];
    __shared__ __align__(16) half_t obuf[DIMC];   // staged roped outputs (f16)

    #pragma unroll
    for (int sel = 0; sel < 2; ++sel) {
        half_t* row = base + sel * DIMC;
        const float* scp = sel ? k_scale : q_scale;

        half4 xh = *(const half4*)(row + 4 * t);
        float x0 = (float)xh[0], x1 = (float)xh[1], x2 = (float)xh[2], x3 = (float)xh[3];
        float ss = x0 * x0 + x1 * x1 + x2 * x2 + x3 * x3;
        #pragma unroll
        for (int o = 32; o >= 1; o >>= 1) ss += __shfl_xor(ss, o);
        if ((t & 63) == 0) red[t >> 6] = ss;
        __syncthreads();

        const float rinv = rsqrtf((red[0] + red[1] + red[2] + red[3]) * (1.0f / DIMC) + 1e-6f);
        float4 g = *(const float4*)(scp + 4 * t);
        buf[4 * t + 0] = x0 * rinv * g.x;
        buf[4 * t + 1] = x1 * rinv * g.y;
        buf[4 * t + 2] = x2 * rinv * g.z;
        buf[4 * t + 3] = x3 * rinv * g.w;
        __syncthreads();

        const float qsc = sel ? 1.0f : (0.125f * LOG2E);  // log2-domain scores

        #pragma unroll
        for (int pp = 0; pp < 2; ++pp) {
            const int p = t + pp * 256;
            const int h = p >> 5;
            const int r = p & 31;
            const int j = r & 15;
            const float pos = (r < 16) ? rowp : colp;
            const int d1 = (r < 16) ? j : (32 + j);   // within-head dim
            const int d2 = d1 + 16;
            const float freq = exp2f((float)j * -0.83048202372f);
            const float ang  = pos * freq;
            float sn, cs;
            __sincosf(ang, &sn, &cs);
            const float a1 = buf[h * HD + d1], a2 = buf[h * HD + d2];
            obuf[h * HD + d1] = (half_t)((a1 * cs - a2 * sn) * qsc);
            obuf[h * HD + d2] = (half_t)((a2 * cs + a1 * sn) * qsc);
        }
        __syncthreads();

        // ---- vectorized store: 128 threads x one half8 (16B) each ----
        if (t < 128) {
            if (sel == 0) {
                *(half8*)(row + t * 8) = *(const half8*)(obuf + t * 8);
            } else {
                const int h = t >> 3, grp = t & 7;
                half_t* kdst = Kf + ((size_t)(b * HH + h) * 72 + c) * 2048;
                const int off = (((ktile << 1) + (grp >> 2)) << 9)
                              + ((((grp & 3) << 4) + krow) << 3);
                *(half8*)(kdst + off) = *(const half8*)(obuf + h * HD + grp * 8);
            }
        }
        __syncthreads();   // buf/red/obuf reused by next sel
    }
}

// ---------------------------------------------------------------------------
// Flash attention v17 (r11, PROVEN ~46-48us): 96-row q-tile, 768 blocks =
// exactly 3/CU, no-max softmax, K=32 PV, dist-1 dead-reg prefetch, l via
// ones-row MFMA, O-store to 128-row-blocked attn_h. Unchanged.
// ---------------------------------------------------------------------------
__global__ __launch_bounds__(256, 3)
void flash_attn_mfma17(const half_t* __restrict__ qkvh, const half_t* __restrict__ Kf,
                       const half_t* __restrict__ Vf, half_t* __restrict__ attn_h)
{
    const int flat = blockIdx.x;         // 0..767, XCD-swizzled
    const int xcd  = flat & 7;
    const int idx  = flat >> 3;          // 0..95  (96 per XCD = exactly 4 bh)
    const int bh   = xcd * 4 + idx / 24;
    const int qtb  = idx % 24;
    const int b    = bh >> 4, h = bh & 15;
    const int t    = threadIdx.x;
    const int w    = t >> 6;
    const int qh   = w >> 1;             // wave's q-half (48 rows)
    const int jt   = w & 1;              // wave's chunk parity
    const int lane = t & 63;
    const int l15  = lane & 15, quad = lane >> 4;

    const size_t tb = (size_t)b * SS;
    const int q0 = qtb * 96;

    __shared__ float mlb[4][48];         // per-wave l for its 48 q's
    __shared__ float Ob[2][64][49];      // [qh][d][q(48)], padded stride 49

    // Q B-frags (loop invariant): B[k=quad*8+i][n=l15], 3 q-tiles x 2 d-groups
    half8 qf[3][2];
    #pragma unroll
    for (int qt = 0; qt < 3; ++qt)
        #pragma unroll
        for (int dg = 0; dg < 2; ++dg)
            qf[qt][dg] = *(const half8*)(qkvh + (tb + q0 + qh * 48 + qt * 16 + l15) * 3072
                                          + h * HD + dg * 32 + quad * 8);

    // ones A-frag: A[m][k] = (m==0). Lane (l15,quad) holds A[l15][quad*8+i].
    const half8 onesA = (l15 == 0)
        ? (half8){(half_t)1, (half_t)1, (half_t)1, (half_t)1,
                  (half_t)1, (half_t)1, (half_t)1, (half_t)1}
        : (half8){(half_t)0, (half_t)0, (half_t)0, (half_t)0,
                  (half_t)0, (half_t)0, (half_t)0, (half_t)0};

    f32x4 acc[4][3];                     // [dt][qt] : O^T[dt*16+quad*4+reg][q]
    f32x4 acc5[3];                       // l-row: acc5[qt][0]@quad0 = l(q=l15)
    #pragma unroll
    for (int qt = 0; qt < 3; ++qt) {
        acc5[qt] = (f32x4){0.f, 0.f, 0.f, 0.f};
        #pragma unroll
        for (int dt = 0; dt < 4; ++dt) acc[dt][qt] = (f32x4){0.f, 0.f, 0.f, 0.f};
    }

    // wave's chunk pointers: wave-chunk p -> global chunk (2p + jt)
    const half_t* kpl = Kf + (size_t)bh * 147456 + jt * 2048 + lane * 8;
    const half_t* vpl = Vf + (size_t)bh * 147456 + jt * 2048 + lane * 8;

    // initial chunk (separate K and V buffers)
    half8 k00 = *(const half8*)(kpl);            // tile0, d 0..31
    half8 k01 = *(const half8*)(kpl + 512);      // tile0, d 32..63
    half8 k10 = *(const half8*)(kpl + 1024);     // tile1, d 0..31
    half8 k11 = *(const half8*)(kpl + 1536);     // tile1, d 32..63
    half8 v0  = *(const half8*)(vpl);            // dt A-frags (k=slot)
    half8 v1  = *(const half8*)(vpl + 512);
    half8 v2  = *(const half8*)(vpl + 1024);
    half8 v3  = *(const half8*)(vpl + 1536);

    const f32x4 initC = (f32x4){-4.f, -4.f, -4.f, -4.f};   // P = exp2(s - 4)

    for (int p = 0; p < 36; ++p) {
        // ---- S^T both 16-row tiles x 3 q-tiles (k regs dead afterwards) ----
        f32x4 scA[3], scB[3];
        __builtin_amdgcn_s_setprio(1);
        #pragma unroll
        for (int qt = 0; qt < 3; ++qt) {
            scA[qt] = initC;
            scA[qt] = __builtin_amdgcn_mfma_f32_16x16x32_f16(k00, qf[qt][0], scA[qt], 0, 0, 0);
            scA[qt] = __builtin_amdgcn_mfma_f32_16x16x32_f16(k01, qf[qt][1], scA[qt], 0, 0, 0);
            scB[qt] = initC;
            scB[qt] = __builtin_amdgcn_mfma_f32_16x16x32_f16(k10, qf[qt][0], scB[qt], 0, 0, 0);
            scB[qt] = __builtin_amdgcn_mfma_f32_16x16x32_f16(k11, qf[qt][1], scB[qt], 0, 0, 0);
        }
        __builtin_amdgcn_s_setprio(0);

        // ---- prefetch next chunk's K into the now-dead k regs ----
        if (p + 1 < 36) {
            const half_t* kN = kpl + (size_t)(p + 1) * 4096;
            k00 = *(const half8*)(kN);
            k01 = *(const half8*)(kN + 512);
            k10 = *(const half8*)(kN + 1024);
            k11 = *(const half8*)(kN + 1536);
        }

        // ---- no-max softmax: P = exp2(s-4) directly (l done by MFMA) ----
        half8 pf[3];
        #pragma unroll
        for (int qt = 0; qt < 3; ++qt) {
            const float a0 = EXP2(scA[qt][0]);
            const float a1 = EXP2(scA[qt][1]);
            const float a2 = EXP2(scA[qt][2]);
            const float a3 = EXP2(scA[qt][3]);
            const float b0 = EXP2(scB[qt][0]);
            const float b1 = EXP2(scB[qt][1]);
            const float b2 = EXP2(scB[qt][2]);
            const float b3 = EXP2(scB[qt][3]);
            // lane quad q' holds P for slots 8q'..8q'+7 -> contiguous B-frag
            pf[qt] = (half8){(half_t)a0, (half_t)a1, (half_t)a2, (half_t)a3,
                             (half_t)b0, (half_t)b1, (half_t)b2, (half_t)b3};
        }

        // ---- O^T += V^T.P^T ; l-row += 1.P^T (v regs dead afterwards) ----
        __builtin_amdgcn_s_setprio(1);
        #pragma unroll
        for (int dt = 0; dt < 4; ++dt) {
            const half8 vf = (dt == 0) ? v0 : (dt == 1) ? v1 : (dt == 2) ? v2 : v3;
            #pragma unroll
            for (int qt = 0; qt < 3; ++qt)
                acc[dt][qt] = __builtin_amdgcn_mfma_f32_16x16x32_f16(
                    vf, pf[qt], acc[dt][qt], 0, 0, 0);
        }
        #pragma unroll
        for (int qt = 0; qt < 3; ++qt)
            acc5[qt] = __builtin_amdgcn_mfma_f32_16x16x32_f16(
                onesA, pf[qt], acc5[qt], 0, 0, 0);
        __builtin_amdgcn_s_setprio(0);

        // ---- prefetch next chunk's V into the now-dead v regs ----
        if (p + 1 < 36) {
            const half_t* vN = vpl + (size_t)(p + 1) * 4096;
            v0 = *(const half8*)(vN);
            v1 = *(const half8*)(vN + 512);
            v2 = *(const half8*)(vN + 1024);
            v3 = *(const half8*)(vN + 1536);
        }
    }

    // ---- 2-way merge across jt waves, per q-half (l from acc5 row 0) ----
    #pragma unroll
    for (int qt = 0; qt < 3; ++qt)
        if (quad == 0) mlb[w][qt * 16 + l15] = acc5[qt][0];
    __syncthreads();

    float fac[3];
    #pragma unroll
    for (int qt = 0; qt < 3; ++qt) {
        const int q = qt * 16 + l15;
        fac[qt] = 1.0f / (mlb[qh * 2 + 0][q] + mlb[qh * 2 + 1][q]);
    }

    #pragma unroll
    for (int ph = 0; ph < 2; ++ph) {
        if (jt == ph) {
            #pragma unroll
            for (int dt = 0; dt < 4; ++dt)
                #pragma unroll
                for (int qt = 0; qt < 3; ++qt)
                    #pragma unroll
                    for (int rg = 0; rg < 4; ++rg) {
                        const int d = dt * 16 + quad * 4 + rg;
                        const int q = qt * 16 + l15;
                        const float v = acc[dt][qt][rg] * fac[qt];
                        if (ph == 0) Ob[qh][d][q] = v;
                        else         Ob[qh][d][q] += v;
                    }
        }
        __syncthreads();
    }

    // ---- store O as f16, tile-blocked [mb][kb][128][32] for the proj GEMM ----
    // 96 rows x 64 d = 6144 halfs; 3 groups of 32 rows, 8 threads/row x 8 d.
    #pragma unroll
    for (int g2 = 0; g2 < 3; ++g2) {
        const int q  = g2 * 32 + (t >> 3);   // 0..95
        const int ds = (t & 7) * 8;          // 0..56, 8-aligned
        const int qh2 = (q >= 48) ? 1 : 0;
        const int qq  = q - 48 * qh2;
        const size_t mrow = tb + q0 + q;
        const int mb2 = (int)(mrow >> 7);
        const int mm  = (int)(mrow & 127);
        const int kb2 = (h * HD + ds) >> 5;
        const int kk  = ds & 31;
        half8 o;
        #pragma unroll
        for (int ii = 0; ii < 8; ++ii) o[ii] = (half_t)Ob[qh2][ds + ii][qq];
        *(half8*)(attn_h + ((size_t)mb2 * 32 + kb2) * 4096 + mm * 32 + kk) = o;
    }
}

// ---------------------------------------------------------------------------
// Launch
// ---------------------------------------------------------------------------
extern "C" void kernel_launch(void* const* d_in, const int* in_sizes, int n_in,
                              void* d_out, int out_size, void* d_ws, size_t ws_size,
                              hipStream_t stream)
{
    const float* input   = (const float*)d_in[0];
    const float* qkv_w   = (const float*)d_in[1];
    const float* qkv_b   = (const float*)d_in[2];
    const float* q_scale = (const float*)d_in[3];
    const float* k_scale = (const float*)d_in[4];
    const float* proj_w  = (const float*)d_in[5];
    const float* proj_b  = (const float*)d_in[6];
    const int*   width   = (const int*)d_in[8];
    float* out = (float*)d_out;

    // ws layout (all f16): qkv_h 28.3MB | attn_h 9.4 | Vf 9.4 | Ah 9.4 (reused
    // as Kf after GEMM1) | Bh1 6.3 | Bh2 2.1  => 65.0 MB total
    half_t* qkvh   = (half_t*)d_ws;
    half_t* attn_h = qkvh   + (size_t)4608 * 3072;
    half_t* Vf     = attn_h + (size_t)4608 * 1024;
    half_t* Ah     = Vf     + (size_t)32 * 72 * 2048;
    half_t* Bh1    = Ah     + (size_t)4608 * 1024;
    half_t* Bh2    = Bh1    + (size_t)3072 * 1024;
    half_t* Kf     = Ah;    // Ah is dead after GEMM1; Kf is written by normrope

    const int M = BB * SS;   // 4608

    // 0) fp32 -> f16 tile-blocked converters, FUSED into one dispatch
    convert_all_f16<<<dim3(72, 32), 256, 0, stream>>>(input, qkv_w, proj_w,
                                                      Ah, Bh1, Bh2);

    // 1) qkv_h = f16( input @ qkv_w^T + qkv_b )  -- 192x96 tiles, 768 blocks
    gemm_mfma192<<<dim3(3 * DIMC / 96, M / 192), 256, 0, stream>>>(
        Ah, Bh1, qkv_b, qkvh);

    // 2) RMSNorm + RoPE: Q in place (log2-scaled), K -> Kf, V -> Vf
    normrope_v8<<<M, 256, 0, stream>>>(qkvh, q_scale, k_scale, width, Kf, Vf);

    // 3) MFMA flash attention -> attn_h (f16, 128-row-blocked), XCD-swizzled
    flash_attn_mfma17<<<dim3(768), 256, 0, stream>>>(qkvh, Kf, Vf, attn_h);

    // 4) out = attn @ proj_w^T + proj_b  -- 128x64 tiles, 2-phase pipeline
    gemm2_128x64<<<dim3(DINC / 64, M / 128), 256, 0, stream>>>(
        attn_h, Bh2, proj_b, out);
}